// Round 1
// baseline (157.987 us; speedup 1.0000x reference)
//
#include <hip/hip_runtime.h>

// EncoderLayer_36352603193491:
//   codes = census LBP of images [256,128,128] (zero-padded 3x3, 8 neighbors)
//   x = codes/127.5 - 1
//   thr = cumsum(normalized relu(lat)+1e-5) * 2 - 1   (8 thresholds)
//   out[b,h,w,t] = (x >= thr[t]) ? 1.0f : 0.0f        -> [256,128,128,8] f32
//
// Memory-bound: 128 MiB write + 16 MiB read. One thread per pixel, two
// float4 stores. Float thresholds are folded into integer code cutoffs
// (exact, via monotonicity of c -> c*s-1) computed once per block by 8 lanes.

#define BN 256
#define HN 128
#define WN 128

__global__ __launch_bounds__(256) void lbp_glt_kernel(
    const float* __restrict__ img,
    const float* __restrict__ lat,
    float* __restrict__ out)
{
    __shared__ int s_cmin[8];
    const int tid = threadIdx.x;

    if (tid < 8) {
        // Replicate reference float32 numerics exactly (no fma contraction).
        float pos[8];
        #pragma unroll
        for (int i = 0; i < 8; ++i) {
            float v = lat[i];
            v = v > 0.0f ? v : 0.0f;          // relu
            pos[i] = __fadd_rn(v, 1e-5f);
        }
        // numpy pairwise-sum order for n == 8: ((p0+p1)+(p2+p3)) + ((p4+p5)+(p6+p7))
        float total = __fadd_rn(
            __fadd_rn(__fadd_rn(pos[0], pos[1]), __fadd_rn(pos[2], pos[3])),
            __fadd_rn(__fadd_rn(pos[4], pos[5]), __fadd_rn(pos[6], pos[7])));
        // sequential cumsum of pos[i]/total up to this lane's index
        float cum = 0.0f;
        for (int i = 0; i <= tid; ++i)
            cum = __fadd_rn(cum, __fdiv_rn(pos[i], total));
        const float thr = __fsub_rn(__fmul_rn(cum, 2.0f), 1.0f);

        // smallest integer code c in [0,256] with (c*s - 1) >= thr
        const float s = (float)(1.0 / 127.5);  // matches np.float32(1.0/127.5)
        int g = (int)ceilf((thr + 1.0f) * 127.5f);
        if (g < 0) g = 0;
        if (g > 256) g = 256;
        while (g > 0) {
            float x = __fsub_rn(__fmul_rn((float)(g - 1), s), 1.0f);
            if (x >= thr) --g; else break;
        }
        while (g < 256) {
            float x = __fsub_rn(__fmul_rn((float)g, s), 1.0f);
            if (x < thr) ++g; else break;
        }
        s_cmin[tid] = g;
    }
    __syncthreads();

    const long long p = (long long)blockIdx.x * 256 + tid;  // flat pixel index
    const int x = (int)(p & (WN - 1));
    const int y = (int)((p >> 7) & (HN - 1));
    const int b = (int)(p >> 14);

    const float* base = img + ((size_t)b << 14) + ((size_t)y << 7) + x;
    const float c = base[0];

    const bool ym = (y > 0), yp = (y < HN - 1);
    const bool xm = (x > 0), xp = (x < WN - 1);

    const float v_tl = (ym && xm) ? base[-WN - 1] : 0.0f;
    const float v_tc = ym         ? base[-WN]     : 0.0f;
    const float v_tr = (ym && xp) ? base[-WN + 1] : 0.0f;
    const float v_r  = xp         ? base[1]       : 0.0f;
    const float v_br = (yp && xp) ? base[WN + 1]  : 0.0f;
    const float v_bc = yp         ? base[WN]      : 0.0f;
    const float v_bl = (yp && xm) ? base[WN - 1]  : 0.0f;
    const float v_l  = xm         ? base[-1]      : 0.0f;

    const int code = (v_tl >= c ?   1 : 0)
                   | (v_tc >= c ?   2 : 0)
                   | (v_tr >= c ?   4 : 0)
                   | (v_r  >= c ?   8 : 0)
                   | (v_br >= c ?  16 : 0)
                   | (v_bc >= c ?  32 : 0)
                   | (v_bl >= c ?  64 : 0)
                   | (v_l  >= c ? 128 : 0);

    const float4 o0 = make_float4(code >= s_cmin[0] ? 1.0f : 0.0f,
                                  code >= s_cmin[1] ? 1.0f : 0.0f,
                                  code >= s_cmin[2] ? 1.0f : 0.0f,
                                  code >= s_cmin[3] ? 1.0f : 0.0f);
    const float4 o1 = make_float4(code >= s_cmin[4] ? 1.0f : 0.0f,
                                  code >= s_cmin[5] ? 1.0f : 0.0f,
                                  code >= s_cmin[6] ? 1.0f : 0.0f,
                                  code >= s_cmin[7] ? 1.0f : 0.0f);

    float4* op = (float4*)(out + (size_t)p * 8);
    op[0] = o0;
    op[1] = o1;
}

extern "C" void kernel_launch(void* const* d_in, const int* in_sizes, int n_in,
                              void* d_out, int out_size, void* d_ws, size_t ws_size,
                              hipStream_t stream) {
    const float* img = (const float*)d_in[0];
    const float* lat = (const float*)d_in[1];
    float* out = (float*)d_out;

    const int n_pix = BN * HN * WN;          // 4,194,304
    const int blocks = n_pix / 256;          // 16,384
    lbp_glt_kernel<<<dim3(blocks), dim3(256), 0, stream>>>(img, lat, out);
}